// Round 1
// baseline (4670.131 us; speedup 1.0000x reference)
//
#include <hip/hip_runtime.h>
#include <math.h>

// ---------------- problem constants ----------------
#define NN 98304            // nodes = B*S*G
#define CC 12               // node channels
#define EE 1572864          // edges (before self-loops)
#define ETOT (EE + NN)      // edges + self loops
#define BB 4
#define SS 512
#define DD 576              // d_model = G*C
#define HH 3                // heads
#define HDI 192             // head dim
#define FFD 2048
#define MR (BB*SS)          // 2048 token rows
#define ND (NN*CC)          // 1179648 == MR*DD
#define ATT_SCALE 0.07216878364870323f  // 1/sqrt(192)

// ---------------- GAT kernels ----------------
__global__ __launch_bounds__(256) void gat_node_k(
    const float* __restrict__ xin, const float* __restrict__ mask,
    const float* __restrict__ noise,
    const float* __restrict__ W, const float* __restrict__ a_s,
    const float* __restrict__ a_d,
    float* __restrict__ xp, float* __restrict__ sval, float* __restrict__ dval,
    int blend)
{
    int n = blockIdx.x * 256 + threadIdx.x;
    if (n >= NN) return;
    float h[CC];
#pragma unroll
    for (int c = 0; c < CC; ++c) {
        float v = xin[n*CC + c];
        if (blend) { float m = mask[n*CC+c]; v = v*m + noise[n*CC+c]*(1.0f-m); }
        h[c] = v;
    }
    float sv = 0.f, dv = 0.f;
#pragma unroll
    for (int oc = 0; oc < CC; ++oc) {
        float a = 0.f;
#pragma unroll
        for (int ic = 0; ic < CC; ++ic) a += h[ic]*W[oc*CC+ic];
        xp[n*CC+oc] = a;
        sv += a * a_s[oc]; dv += a * a_d[oc];
    }
    sval[n] = sv; dval[n] = dv;
}

__device__ __forceinline__ unsigned f2sort(float f) {
    unsigned b = __float_as_uint(f);
    return (b & 0x80000000u) ? ~b : (b | 0x80000000u);
}
__device__ __forceinline__ float sort2f(unsigned u) {
    return (u & 0x80000000u) ? __uint_as_float(u ^ 0x80000000u)
                             : __uint_as_float(~u);
}

__global__ __launch_bounds__(256) void gat_edge_a(
    const int* __restrict__ e0, const int* __restrict__ e1,
    const float* __restrict__ sval, const float* __restrict__ dval,
    float* __restrict__ ebuf, unsigned* __restrict__ mbuf)
{
    for (long long i = blockIdx.x*256LL + threadIdx.x; i < ETOT; i += (long long)gridDim.x*256) {
        int s = (i < EE) ? e0[i] : (int)(i - EE);
        int d = (i < EE) ? e1[i] : (int)(i - EE);
        float e = sval[s] + dval[d];
        e = e > 0.f ? e : 0.2f*e;
        ebuf[i] = e;
        atomicMax(&mbuf[d], f2sort(e));
    }
}

__global__ __launch_bounds__(256) void gat_edge_b(
    const int* __restrict__ e0, const int* __restrict__ e1,
    const float* __restrict__ ebuf, const unsigned* __restrict__ mbuf,
    const float* __restrict__ xp, float* __restrict__ acc,
    float* __restrict__ denom)
{
    for (long long i = blockIdx.x*256LL + threadIdx.x; i < ETOT; i += (long long)gridDim.x*256) {
        int s = (i < EE) ? e0[i] : (int)(i - EE);
        int d = (i < EE) ? e1[i] : (int)(i - EE);
        float m = sort2f(mbuf[d]);
        float w = expf(ebuf[i] - m);
        atomicAdd(&denom[d], w);
#pragma unroll
        for (int c = 0; c < CC; ++c)
            atomicAdd(&acc[d*CC + c], w * xp[s*CC + c]);
    }
}

__global__ __launch_bounds__(256) void gat_fin_k(
    const float* __restrict__ acc, const float* __restrict__ denom,
    const float* __restrict__ bias, float* __restrict__ out, int dotanh)
{
    int i = blockIdx.x*256 + threadIdx.x;
    if (i >= ND) return;
    int n = i / CC, c = i % CC;
    float r = acc[i] / denom[n] + bias[c];
    if (dotanh) r = tanhf(r);
    out[i] = r;
}

// ---------------- generic NT GEMM: C[M,N] = A[M,K] @ W[N,K]^T + bias ----------------
#define BM 64
#define BN 64
#define BKK 16
__global__ __launch_bounds__(256) void gemm_nt(
    const float* __restrict__ A, const float* __restrict__ Bw,
    const float* __restrict__ bias, float* __restrict__ C,
    int M, int Nn, int K, int relu)
{
    __shared__ float As[BKK][BM+1];
    __shared__ float Bs[BKK][BN+1];
    int bm = blockIdx.y * BM;
    int bn = blockIdx.x * BN;
    int tid = threadIdx.x;
    int tx = tid & 15, ty = tid >> 4;
    float acc[4][4] = {};
    for (int k0 = 0; k0 < K; k0 += BKK) {
#pragma unroll
        for (int p = 0; p < 4; ++p) {
            int r = (tid >> 4) + p * 16;
            int c = tid & 15;
            As[c][r] = A[(size_t)(bm + r) * K + (k0 + c)];
            Bs[c][r] = Bw[(size_t)(bn + r) * K + (k0 + c)];
        }
        __syncthreads();
#pragma unroll
        for (int kk = 0; kk < BKK; ++kk) {
            float a[4], b[4];
#pragma unroll
            for (int i = 0; i < 4; ++i) a[i] = As[kk][ty*4+i];
#pragma unroll
            for (int j = 0; j < 4; ++j) b[j] = Bs[kk][tx*4+j];
#pragma unroll
            for (int i = 0; i < 4; ++i)
#pragma unroll
                for (int j = 0; j < 4; ++j)
                    acc[i][j] += a[i]*b[j];
        }
        __syncthreads();
    }
#pragma unroll
    for (int i = 0; i < 4; ++i) {
        int m = bm + ty*4 + i;
#pragma unroll
        for (int j = 0; j < 4; ++j) {
            int n = bn + tx*4 + j;
            float v = acc[i][j] + bias[n];
            if (relu) v = fmaxf(v, 0.f);
            C[(size_t)m * Nn + n] = v;
        }
    }
}

// ---------------- attention: one q-row per block ----------------
__global__ __launch_bounds__(256) void attn_k(
    const float* __restrict__ q, const float* __restrict__ k,
    const float* __restrict__ v, float* __restrict__ o)
{
    int blk = blockIdx.x;
    int qi = blk % SS; int bh = blk / SS; int h = bh % HH; int b = bh / HH;
    __shared__ float qs[HDI];
    __shared__ float sc[SS];
    __shared__ float red[256];
    int tid = threadIdx.x;
    const size_t rowbase = (size_t)(b*SS + qi)*DD + h*HDI;
    if (tid < HDI) qs[tid] = q[rowbase + tid];
    __syncthreads();
    for (int j = tid; j < SS; j += 256) {
        const float* krow = k + ((size_t)(b*SS + j)*DD + h*HDI);
        float s = 0.f;
        for (int d = 0; d < HDI; ++d) s += qs[d]*krow[d];
        sc[j] = s * ATT_SCALE;
    }
    __syncthreads();
    float lm = -1e30f;
    for (int j = tid; j < SS; j += 256) lm = fmaxf(lm, sc[j]);
    red[tid] = lm; __syncthreads();
    for (int off = 128; off > 0; off >>= 1) {
        if (tid < off) red[tid] = fmaxf(red[tid], red[tid+off]);
        __syncthreads();
    }
    float mx = red[0];
    __syncthreads();
    float ls = 0.f;
    for (int j = tid; j < SS; j += 256) { float e = expf(sc[j]-mx); sc[j] = e; ls += e; }
    red[tid] = ls; __syncthreads();
    for (int off = 128; off > 0; off >>= 1) {
        if (tid < off) red[tid] += red[tid+off];
        __syncthreads();
    }
    float inv = 1.f / red[0];
    if (tid < HDI) {
        float acc = 0.f;
        for (int j = 0; j < SS; ++j)
            acc += sc[j] * v[(size_t)(b*SS + j)*DD + h*HDI + tid];
        o[rowbase + tid] = acc * inv;
    }
}

// ---------------- layernorm over D=576, input = a (+ r) ----------------
__global__ __launch_bounds__(256) void ln_k(
    const float* __restrict__ a, const float* __restrict__ r,
    const float* __restrict__ g, const float* __restrict__ be,
    float* __restrict__ out)
{
    int row = blockIdx.x; int tid = threadIdx.x;
    __shared__ float red[256], red2[256];
    size_t base = (size_t)row * DD;
    float x0 = a[base+tid]      + r[base+tid];
    float x1 = a[base+tid+256]  + r[base+tid+256];
    float x2 = (tid < 64) ? (a[base+tid+512] + r[base+tid+512]) : 0.f;
    float s  = x0+x1+x2;
    float s2 = x0*x0 + x1*x1 + x2*x2;
    red[tid] = s; red2[tid] = s2; __syncthreads();
    for (int off = 128; off > 0; off >>= 1) {
        if (tid < off) { red[tid] += red[tid+off]; red2[tid] += red2[tid+off]; }
        __syncthreads();
    }
    float mean = red[0] / (float)DD;
    float var  = red2[0] / (float)DD - mean*mean;
    float inv = rsqrtf(var + 1e-5f);
    out[base+tid]     = (x0-mean)*inv*g[tid]     + be[tid];
    out[base+tid+256] = (x1-mean)*inv*g[tid+256] + be[tid+256];
    if (tid < 64)
        out[base+tid+512] = (x2-mean)*inv*g[tid+512] + be[tid+512];
}

// ---------------- conv helpers ----------------
// w[co][ci][k] -> wT[co][k][ci]
__global__ __launch_bounds__(256) void wtrans_k(
    const float* __restrict__ w, float* __restrict__ wT, int Cout, int Cin)
{
    int total = Cout * Cin * 3;
    for (int i = blockIdx.x*256 + threadIdx.x; i < total; i += gridDim.x*256) {
        int co = i / (Cin*3); int rem = i % (Cin*3);
        int ci = rem / 3; int kk = rem % 3;
        wT[(size_t)co*Cin*3 + kk*Cin + ci] = w[i];
    }
}

// im2col from time-major [B, Lin, Cin] activations -> col[B*Lout][3*Cin] (k-major)
// mode 0: normal; mode 1: nearest-upsample x2 source (valid sl in [0,2*Lin));
// mode 2: channel-concat of s0,s1 (each Cin/2)
__global__ __launch_bounds__(256) void im2col_k(
    const float* __restrict__ s0, const float* __restrict__ s1,
    float* __restrict__ col, int Lout, int Lin, int Cin,
    int stride, int pad, int mode)
{
    long long total = (long long)BB * Lout * Cin * 3;
    for (long long i = blockIdx.x*256LL + threadIdx.x; i < total; i += (long long)gridDim.x*256) {
        int j = (int)(i % (Cin*3));
        long long m = i / (Cin*3);
        int l = (int)(m % Lout); int b = (int)(m / Lout);
        int kk = j / Cin; int ci = j % Cin;
        int sl = l*stride + kk - pad;
        int Lsrc = (mode == 1) ? Lin*2 : Lin;
        float v = 0.f;
        if (sl >= 0 && sl < Lsrc) {
            if (mode == 1)       v = s0[((size_t)b*Lin + (sl >> 1))*Cin + ci];
            else if (mode == 2)  v = (ci < Cin/2)
                                   ? s0[((size_t)b*Lin + sl)*(Cin/2) + ci]
                                   : s1[((size_t)b*Lin + sl)*(Cin/2) + (ci - Cin/2)];
            else                 v = s0[((size_t)b*Lin + sl)*Cin + ci];
        }
        col[i] = v;
    }
}

// ---------------- launch ----------------
extern "C" void kernel_launch(void* const* d_in, const int* in_sizes, int n_in,
                              void* d_out, int out_size, void* d_ws, size_t ws_size,
                              hipStream_t stream)
{
    const int*   edge   = (const int*)  d_in[0];
    const float* x      = (const float*)d_in[1];
    const float* mask   = (const float*)d_in[2];
    const float* noise  = (const float*)d_in[3];
    const float* W_enc  = (const float*)d_in[4];
    const float* asrc_e = (const float*)d_in[5];
    const float* adst_e = (const float*)d_in[6];
    const float* b_enc  = (const float*)d_in[7];
    const float* Wq = (const float*)d_in[8];  const float* bq = (const float*)d_in[9];
    const float* Wk = (const float*)d_in[10]; const float* bk = (const float*)d_in[11];
    const float* Wv = (const float*)d_in[12]; const float* bv = (const float*)d_in[13];
    const float* Wo = (const float*)d_in[14]; const float* bo = (const float*)d_in[15];
    const float* ln1g = (const float*)d_in[16]; const float* ln1b = (const float*)d_in[17];
    const float* W1 = (const float*)d_in[18]; const float* b1 = (const float*)d_in[19];
    const float* W2 = (const float*)d_in[20]; const float* b2 = (const float*)d_in[21];
    const float* ln2g = (const float*)d_in[22]; const float* ln2b = (const float*)d_in[23];
    const float* enc1_w = (const float*)d_in[24]; const float* enc1_b = (const float*)d_in[25];
    const float* down_w = (const float*)d_in[26]; const float* down_b = (const float*)d_in[27];
    const float* bott_w = (const float*)d_in[28]; const float* bott_b = (const float*)d_in[29];
    const float* up_w   = (const float*)d_in[30]; const float* up_b   = (const float*)d_in[31];
    const float* dec_w  = (const float*)d_in[32]; const float* dec_b  = (const float*)d_in[33];
    const float* W_dec  = (const float*)d_in[34];
    const float* asrc_d = (const float*)d_in[35];
    const float* adst_d = (const float*)d_in[36];
    const float* b_dec  = (const float*)d_in[37];
    float* out = (float*)d_out;

    float* ws = (float*)d_ws;
    // static layout (floats); total 24,395,776 floats = 97.6 MB
    float*    xp    = ws;                      // 1179648
    float*    sval  = ws + 1179648;            // 98304
    float*    dval  = ws + 1277952;            // 98304
    unsigned* mbuf  = (unsigned*)(ws + 1376256);// 98304
    float*    denom = ws + 1474560;            // 98304
    float*    ebuf  = ws + 1572864;            // 1671168
    float*    t     = ws + 3244032;            // 1179648
    float*    q     = ws + 4423680;            // 1179648
    float*    k     = ws + 5603328;            // 1179648
    float*    v     = ws + 6782976;            // 1179648
    float*    o     = ws + 7962624;            // 1179648
    float*    t1    = ws + 9142272;            // 1179648
    float*    ff1   = ws + 10321920;           // 4194304
    float*    e1    = ws + 14516224;           // 1179648
    float*    d1    = ws + 15695872;           // 1179648
    float*    btb   = ws + 16875520;           // 1179648
    float*    up    = ws + 18055168;           // 1179648
    float*    dec   = ws + 19234816;           // 1179648
    float*    wT    = ws + 20414464;           // 3981312 (max conv wt)
    float*    col   = q;                       // alias over dead q..ff1 (7077888)

    const int* e0 = edge;
    const int* e1i = edge + EE;

    // ---- 1. GAT encoder ----
    gat_node_k<<<NN/256, 256, 0, stream>>>(x, mask, noise, W_enc, asrc_e, adst_e,
                                           xp, sval, dval, 1);
    hipMemsetAsync(mbuf, 0, NN*sizeof(unsigned), stream);
    gat_edge_a<<<ETOT/256, 256, 0, stream>>>(e0, e1i, sval, dval, ebuf, mbuf);
    hipMemsetAsync(denom, 0, NN*sizeof(float), stream);
    hipMemsetAsync(t, 0, (size_t)ND*sizeof(float), stream);
    gat_edge_b<<<ETOT/256, 256, 0, stream>>>(e0, e1i, ebuf, mbuf, xp, t, denom);
    gat_fin_k<<<ND/256, 256, 0, stream>>>(t, denom, b_enc, t, 0);

    // ---- 2. transformer layer ----
    dim3 g9(DD/64, MR/64);     // 9 x 32
    dim3 g32(FFD/64, MR/64);   // 32 x 32
    gemm_nt<<<g9, 256, 0, stream>>>(t, Wq, bq, q, MR, DD, DD, 0);
    gemm_nt<<<g9, 256, 0, stream>>>(t, Wk, bk, k, MR, DD, DD, 0);
    gemm_nt<<<g9, 256, 0, stream>>>(t, Wv, bv, v, MR, DD, DD, 0);
    attn_k<<<BB*HH*SS, 256, 0, stream>>>(q, k, v, t1);
    gemm_nt<<<g9, 256, 0, stream>>>(t1, Wo, bo, o, MR, DD, DD, 0);
    ln_k<<<MR, 256, 0, stream>>>(t, o, ln1g, ln1b, t1);
    gemm_nt<<<g32, 256, 0, stream>>>(t1, W1, b1, ff1, MR, FFD, DD, 1);
    gemm_nt<<<g9, 256, 0, stream>>>(ff1, W2, b2, o, MR, DD, FFD, 0);
    ln_k<<<MR, 256, 0, stream>>>(t1, o, ln2g, ln2b, t);

    // ---- 3. UNet1d (time-major activations, im2col + NT GEMM) ----
    // enc1: 576 -> 576, L=512, stride 1, pad (1,1)
    wtrans_k<<<(576*576*3+255)/256, 256, 0, stream>>>(enc1_w, wT, 576, 576);
    im2col_k<<<(BB*512*576*3+255)/256, 256, 0, stream>>>(t, nullptr, col, 512, 512, 576, 1, 1, 0);
    gemm_nt<<<dim3(576/64, 2048/64), 256, 0, stream>>>(col, wT, enc1_b, e1, 2048, 576, 1728, 1);
    // down: 576 -> 1152, L 512->256, stride 2, pad (0,1)
    wtrans_k<<<(1152*576*3+255)/256, 256, 0, stream>>>(down_w, wT, 1152, 576);
    im2col_k<<<(BB*256*576*3+255)/256, 256, 0, stream>>>(e1, nullptr, col, 256, 512, 576, 2, 0, 0);
    gemm_nt<<<dim3(1152/64, 1024/64), 256, 0, stream>>>(col, wT, down_b, d1, 1024, 1152, 1728, 1);
    // bott: 1152 -> 1152, L=256, stride 1, pad (1,1)
    wtrans_k<<<(1152*1152*3+255)/256, 256, 0, stream>>>(bott_w, wT, 1152, 1152);
    im2col_k<<<(BB*256*1152*3+255)/256, 256, 0, stream>>>(d1, nullptr, col, 256, 256, 1152, 1, 1, 0);
    gemm_nt<<<dim3(1152/64, 1024/64), 256, 0, stream>>>(col, wT, bott_b, btb, 1024, 1152, 3456, 1);
    // up: repeat x2 then 1152 -> 576, L=512, stride 1, pad (1,1)
    wtrans_k<<<(576*1152*3+255)/256, 256, 0, stream>>>(up_w, wT, 576, 1152);
    im2col_k<<<(BB*512*1152*3+255)/256, 256, 0, stream>>>(btb, nullptr, col, 512, 256, 1152, 1, 1, 1);
    gemm_nt<<<dim3(576/64, 2048/64), 256, 0, stream>>>(col, wT, up_b, up, 2048, 576, 3456, 1);
    // dec: concat(up, e1) 1152 -> 576, L=512, stride 1, pad (1,1), no relu
    wtrans_k<<<(576*1152*3+255)/256, 256, 0, stream>>>(dec_w, wT, 576, 1152);
    im2col_k<<<(BB*512*1152*3+255)/256, 256, 0, stream>>>(up, e1, col, 512, 512, 1152, 1, 1, 2);
    gemm_nt<<<dim3(576/64, 2048/64), 256, 0, stream>>>(col, wT, dec_b, dec, 2048, 576, 3456, 0);

    // ---- 4. GAT decoder + tanh ----
    gat_node_k<<<NN/256, 256, 0, stream>>>(dec, nullptr, nullptr, W_dec, asrc_d, adst_d,
                                           xp, sval, dval, 0);
    hipMemsetAsync(mbuf, 0, NN*sizeof(unsigned), stream);
    gat_edge_a<<<ETOT/256, 256, 0, stream>>>(e0, e1i, sval, dval, ebuf, mbuf);
    hipMemsetAsync(denom, 0, NN*sizeof(float), stream);
    hipMemsetAsync(t, 0, (size_t)ND*sizeof(float), stream);
    gat_edge_b<<<ETOT/256, 256, 0, stream>>>(e0, e1i, ebuf, mbuf, xp, t, denom);
    gat_fin_k<<<ND/256, 256, 0, stream>>>(t, denom, b_dec, out, 1);
}

// Round 2
// 2499.955 us; speedup vs baseline: 1.8681x; 1.8681x over previous
//
#include <hip/hip_runtime.h>
#include <math.h>

// ---------------- problem constants ----------------
#define NN 98304            // nodes = B*S*G
#define CC 12               // node channels
#define EE 1572864          // edges (before self-loops)
#define ETOT (EE + NN)      // edges + self loops
#define BB 4
#define SS 512
#define DD 576              // d_model = G*C
#define HH 3
#define HDI 192
#define FFD 2048
#define MR (BB*SS)          // 2048 token rows
#define ND (NN*CC)
#define ATT_SCALE 0.07216878364870323f  // 1/sqrt(192)

// ---------------- GAT: node transform ----------------
__global__ __launch_bounds__(256) void gat_node_k(
    const float* __restrict__ xin, const float* __restrict__ mask,
    const float* __restrict__ noise,
    const float* __restrict__ W, const float* __restrict__ a_s,
    const float* __restrict__ a_d,
    float* __restrict__ xp, float* __restrict__ sval, float* __restrict__ dval,
    int blend)
{
    int n = blockIdx.x * 256 + threadIdx.x;
    if (n >= NN) return;
    float h[CC];
#pragma unroll
    for (int c = 0; c < CC; ++c) {
        float v = xin[n*CC + c];
        if (blend) { float m = mask[n*CC+c]; v = v*m + noise[n*CC+c]*(1.0f-m); }
        h[c] = v;
    }
    float sv = 0.f, dv = 0.f;
#pragma unroll
    for (int oc = 0; oc < CC; ++oc) {
        float a = 0.f;
#pragma unroll
        for (int ic = 0; ic < CC; ++ic) a += h[ic]*W[oc*CC+ic];
        xp[n*CC+oc] = a;
        sv += a * a_s[oc]; dv += a * a_d[oc];
    }
    sval[n] = sv; dval[n] = dv;
}

// ---------------- counting sort of edges by dst (built once, reused) ----------------
__global__ __launch_bounds__(256) void hist_k(
    const int* __restrict__ e1, int* __restrict__ cnt)
{
    for (long long i = blockIdx.x*256LL + threadIdx.x; i < ETOT; i += (long long)gridDim.x*256) {
        int d = (i < EE) ? e1[i] : (int)(i - EE);
        atomicAdd(&cnt[d], 1);
    }
}

__global__ __launch_bounds__(256) void scan1_k(
    const int* __restrict__ cnt, int* __restrict__ offs, int* __restrict__ bsum)
{
    __shared__ int sh[256];
    int b = blockIdx.x, t = threadIdx.x;
    int v = cnt[b*256 + t];
    sh[t] = v; __syncthreads();
    for (int off = 1; off < 256; off <<= 1) {
        int add = (t >= off) ? sh[t-off] : 0;
        __syncthreads();
        sh[t] += add;
        __syncthreads();
    }
    offs[b*256 + t] = sh[t] - v;           // exclusive
    if (t == 255) bsum[b] = sh[255];
}

__global__ __launch_bounds__(384) void scan2_k(int* __restrict__ bsum)
{
    __shared__ int sh[384];
    int t = threadIdx.x;
    if (t < 384) sh[t] = bsum[t];
    __syncthreads();
    if (t == 0) { int run = 0; for (int i = 0; i < 384; ++i) { int v = sh[i]; sh[i] = run; run += v; } }
    __syncthreads();
    if (t < 384) bsum[t] = sh[t];
}

__global__ __launch_bounds__(256) void scan3_k(
    int* __restrict__ offs, const int* __restrict__ bsum, int* __restrict__ cursor)
{
    int i = blockIdx.x*256 + threadIdx.x;
    int v = offs[i] + bsum[blockIdx.x];
    offs[i] = v; cursor[i] = v;
}

__global__ __launch_bounds__(256) void scatter_k(
    const int* __restrict__ e0, const int* __restrict__ e1,
    int* __restrict__ cursor, int* __restrict__ perm)
{
    for (long long i = blockIdx.x*256LL + threadIdx.x; i < ETOT; i += (long long)gridDim.x*256) {
        int s = (i < EE) ? e0[i] : (int)(i - EE);
        int d = (i < EE) ? e1[i] : (int)(i - EE);
        int pos = atomicAdd(&cursor[d], 1);
        perm[pos] = s;
    }
}

// ---------------- GAT: segmented gather-aggregate (no atomics, no max pass) ----
__global__ __launch_bounds__(256) void gat_agg_k(
    const int* __restrict__ perm, const int* __restrict__ offs,
    const int* __restrict__ cnt,
    const float* __restrict__ xp, const float* __restrict__ sval,
    const float* __restrict__ dval, const float* __restrict__ bias,
    float* __restrict__ out, int dotanh)
{
    int n = blockIdx.x*256 + threadIdx.x;
    if (n >= NN) return;
    int beg = offs[n], m = cnt[n];
    float dv = dval[n];
    float acc[CC] = {};
    float den = 0.f;
    for (int i = 0; i < m; ++i) {
        int s = perm[beg + i];
        float e = sval[s] + dv;
        e = e > 0.f ? e : 0.2f*e;
        float w = __expf(e);
        den += w;
        const float4* xr = (const float4*)(xp + (size_t)s*CC);
        float4 p0 = xr[0], p1 = xr[1], p2 = xr[2];
        acc[0] += w*p0.x; acc[1] += w*p0.y; acc[2]  += w*p0.z; acc[3]  += w*p0.w;
        acc[4] += w*p1.x; acc[5] += w*p1.y; acc[6]  += w*p1.z; acc[7]  += w*p1.w;
        acc[8] += w*p2.x; acc[9] += w*p2.y; acc[10] += w*p2.z; acc[11] += w*p2.w;
    }
    float inv = 1.f / den;
#pragma unroll
    for (int c = 0; c < CC; ++c) {
        float r = acc[c]*inv + bias[c];
        if (dotanh) r = tanhf(r);
        out[n*CC + c] = r;
    }
}

// ---------------- generic NT GEMM: C[M,N] = A[M,K] @ W[N,K]^T + bias ----------------
#define BM 64
#define BN 64
#define BKK 16
__global__ __launch_bounds__(256) void gemm_nt(
    const float* __restrict__ A, const float* __restrict__ Bw,
    const float* __restrict__ bias, float* __restrict__ C,
    int M, int Nn, int K, int relu)
{
    __shared__ float As[BKK][BM+1];
    __shared__ float Bs[BKK][BN+1];
    int bm = blockIdx.y * BM;
    int bn = blockIdx.x * BN;
    int tid = threadIdx.x;
    int tx = tid & 15, ty = tid >> 4;
    float acc[4][4] = {};
    for (int k0 = 0; k0 < K; k0 += BKK) {
#pragma unroll
        for (int p = 0; p < 4; ++p) {
            int r = (tid >> 4) + p * 16;
            int c = tid & 15;
            As[c][r] = A[(size_t)(bm + r) * K + (k0 + c)];
            Bs[c][r] = Bw[(size_t)(bn + r) * K + (k0 + c)];
        }
        __syncthreads();
#pragma unroll
        for (int kk = 0; kk < BKK; ++kk) {
            float a[4], b[4];
#pragma unroll
            for (int i = 0; i < 4; ++i) a[i] = As[kk][ty*4+i];
#pragma unroll
            for (int j = 0; j < 4; ++j) b[j] = Bs[kk][tx*4+j];
#pragma unroll
            for (int i = 0; i < 4; ++i)
#pragma unroll
                for (int j = 0; j < 4; ++j)
                    acc[i][j] += a[i]*b[j];
        }
        __syncthreads();
    }
#pragma unroll
    for (int i = 0; i < 4; ++i) {
        int m = bm + ty*4 + i;
#pragma unroll
        for (int j = 0; j < 4; ++j) {
            int n = bn + tx*4 + j;
            float v = acc[i][j] + bias[n];
            if (relu) v = fmaxf(v, 0.f);
            C[(size_t)m * Nn + n] = v;
        }
    }
}

// ---------------- attention: one q-row per block ----------------
__global__ __launch_bounds__(256) void attn_k(
    const float* __restrict__ q, const float* __restrict__ k,
    const float* __restrict__ v, float* __restrict__ o)
{
    int blk = blockIdx.x;
    int qi = blk % SS; int bh = blk / SS; int h = bh % HH; int b = bh / HH;
    __shared__ float qs[HDI];
    __shared__ float sc[SS];
    __shared__ float red[256];
    int tid = threadIdx.x;
    const size_t rowbase = (size_t)(b*SS + qi)*DD + h*HDI;
    if (tid < HDI) qs[tid] = q[rowbase + tid];
    __syncthreads();
    for (int j = tid; j < SS; j += 256) {
        const float* krow = k + ((size_t)(b*SS + j)*DD + h*HDI);
        float s = 0.f;
        for (int d = 0; d < HDI; ++d) s += qs[d]*krow[d];
        sc[j] = s * ATT_SCALE;
    }
    __syncthreads();
    float lm = -1e30f;
    for (int j = tid; j < SS; j += 256) lm = fmaxf(lm, sc[j]);
    red[tid] = lm; __syncthreads();
    for (int off = 128; off > 0; off >>= 1) {
        if (tid < off) red[tid] = fmaxf(red[tid], red[tid+off]);
        __syncthreads();
    }
    float mx = red[0];
    __syncthreads();
    float ls = 0.f;
    for (int j = tid; j < SS; j += 256) { float e = expf(sc[j]-mx); sc[j] = e; ls += e; }
    red[tid] = ls; __syncthreads();
    for (int off = 128; off > 0; off >>= 1) {
        if (tid < off) red[tid] += red[tid+off];
        __syncthreads();
    }
    float inv = 1.f / red[0];
    if (tid < HDI) {
        float acc = 0.f;
        for (int j = 0; j < SS; ++j)
            acc += sc[j] * v[(size_t)(b*SS + j)*DD + h*HDI + tid];
        o[rowbase + tid] = acc * inv;
    }
}

// ---------------- layernorm over D=576 ----------------
__global__ __launch_bounds__(256) void ln_k(
    const float* __restrict__ a, const float* __restrict__ r,
    const float* __restrict__ g, const float* __restrict__ be,
    float* __restrict__ out)
{
    int row = blockIdx.x; int tid = threadIdx.x;
    __shared__ float red[256], red2[256];
    size_t base = (size_t)row * DD;
    float x0 = a[base+tid]      + r[base+tid];
    float x1 = a[base+tid+256]  + r[base+tid+256];
    float x2 = (tid < 64) ? (a[base+tid+512] + r[base+tid+512]) : 0.f;
    float s  = x0+x1+x2;
    float s2 = x0*x0 + x1*x1 + x2*x2;
    red[tid] = s; red2[tid] = s2; __syncthreads();
    for (int off = 128; off > 0; off >>= 1) {
        if (tid < off) { red[tid] += red[tid+off]; red2[tid] += red2[tid+off]; }
        __syncthreads();
    }
    float mean = red[0] / (float)DD;
    float var  = red2[0] / (float)DD - mean*mean;
    float inv = rsqrtf(var + 1e-5f);
    out[base+tid]     = (x0-mean)*inv*g[tid]     + be[tid];
    out[base+tid+256] = (x1-mean)*inv*g[tid+256] + be[tid+256];
    if (tid < 64)
        out[base+tid+512] = (x2-mean)*inv*g[tid+512] + be[tid+512];
}

// ---------------- conv helpers ----------------
__global__ __launch_bounds__(256) void wtrans_k(
    const float* __restrict__ w, float* __restrict__ wT, int Cout, int Cin)
{
    int total = Cout * Cin * 3;
    for (int i = blockIdx.x*256 + threadIdx.x; i < total; i += gridDim.x*256) {
        int co = i / (Cin*3); int rem = i % (Cin*3);
        int ci = rem / 3; int kk = rem % 3;
        wT[(size_t)co*Cin*3 + kk*Cin + ci] = w[i];
    }
}

__global__ __launch_bounds__(256) void im2col_k(
    const float* __restrict__ s0, const float* __restrict__ s1,
    float* __restrict__ col, int Lout, int Lin, int Cin,
    int stride, int pad, int mode)
{
    long long total = (long long)BB * Lout * Cin * 3;
    for (long long i = blockIdx.x*256LL + threadIdx.x; i < total; i += (long long)gridDim.x*256) {
        int j = (int)(i % (Cin*3));
        long long m = i / (Cin*3);
        int l = (int)(m % Lout); int b = (int)(m / Lout);
        int kk = j / Cin; int ci = j % Cin;
        int sl = l*stride + kk - pad;
        int Lsrc = (mode == 1) ? Lin*2 : Lin;
        float v = 0.f;
        if (sl >= 0 && sl < Lsrc) {
            if (mode == 1)       v = s0[((size_t)b*Lin + (sl >> 1))*Cin + ci];
            else if (mode == 2)  v = (ci < Cin/2)
                                   ? s0[((size_t)b*Lin + sl)*(Cin/2) + ci]
                                   : s1[((size_t)b*Lin + sl)*(Cin/2) + (ci - Cin/2)];
            else                 v = s0[((size_t)b*Lin + sl)*Cin + ci];
        }
        col[i] = v;
    }
}

// ---------------- launch ----------------
extern "C" void kernel_launch(void* const* d_in, const int* in_sizes, int n_in,
                              void* d_out, int out_size, void* d_ws, size_t ws_size,
                              hipStream_t stream)
{
    const int*   edge   = (const int*)  d_in[0];
    const float* x      = (const float*)d_in[1];
    const float* mask   = (const float*)d_in[2];
    const float* noise  = (const float*)d_in[3];
    const float* W_enc  = (const float*)d_in[4];
    const float* asrc_e = (const float*)d_in[5];
    const float* adst_e = (const float*)d_in[6];
    const float* b_enc  = (const float*)d_in[7];
    const float* Wq = (const float*)d_in[8];  const float* bq = (const float*)d_in[9];
    const float* Wk = (const float*)d_in[10]; const float* bk = (const float*)d_in[11];
    const float* Wv = (const float*)d_in[12]; const float* bv = (const float*)d_in[13];
    const float* Wo = (const float*)d_in[14]; const float* bo = (const float*)d_in[15];
    const float* ln1g = (const float*)d_in[16]; const float* ln1b = (const float*)d_in[17];
    const float* W1 = (const float*)d_in[18]; const float* b1 = (const float*)d_in[19];
    const float* W2 = (const float*)d_in[20]; const float* b2 = (const float*)d_in[21];
    const float* ln2g = (const float*)d_in[22]; const float* ln2b = (const float*)d_in[23];
    const float* enc1_w = (const float*)d_in[24]; const float* enc1_b = (const float*)d_in[25];
    const float* down_w = (const float*)d_in[26]; const float* down_b = (const float*)d_in[27];
    const float* bott_w = (const float*)d_in[28]; const float* bott_b = (const float*)d_in[29];
    const float* up_w   = (const float*)d_in[30]; const float* up_b   = (const float*)d_in[31];
    const float* dec_w  = (const float*)d_in[32]; const float* dec_b  = (const float*)d_in[33];
    const float* W_dec  = (const float*)d_in[34];
    const float* asrc_d = (const float*)d_in[35];
    const float* adst_d = (const float*)d_in[36];
    const float* b_dec  = (const float*)d_in[37];
    float* out = (float*)d_out;

    float* ws = (float*)d_ws;
    // static layout (floats); total 24,395,776 floats = 97.6 MB (same as R0)
    float*    xp    = ws;                      // 1179648
    float*    sval  = ws + 1179648;            // 98304
    float*    dval  = ws + 1277952;            // 98304
    int*      cnt   = (int*)(ws + 1376256);    // 98304
    int*      offs  = (int*)(ws + 1474560);    // 98304
    int*      perm  = (int*)(ws + 1572864);    // 1671168
    float*    t     = ws + 3244032;            // 1179648
    float*    q     = ws + 4423680;            // 1179648
    float*    k     = ws + 5603328;            // 1179648
    float*    v     = ws + 6782976;            // 1179648
    float*    o     = ws + 7962624;            // 1179648
    float*    t1    = ws + 9142272;            // 1179648
    float*    ff1   = ws + 10321920;           // 4194304
    float*    e1    = ws + 14516224;           // 1179648
    float*    d1    = ws + 15695872;           // 1179648
    float*    btb   = ws + 16875520;           // 1179648
    float*    up    = ws + 18055168;           // 1179648
    float*    dec   = ws + 19234816;           // 1179648
    float*    wT    = ws + 20414464;           // 3981312 (max conv wt)
    float*    col   = q;                       // alias over dead q..ff1 during convs
    int*      cursor = (int*)q;                // alias: only live during sort phase
    int*      bsum   = (int*)(q + 98304);      // alias: only live during sort phase

    const int* e0 = edge;
    const int* e1i = edge + EE;

    // ---- 0. build dst-sorted edge permutation (shared by both GATs) ----
    hipMemsetAsync(cnt, 0, NN*sizeof(int), stream);
    hist_k<<<ETOT/256, 256, 0, stream>>>(e1i, cnt);
    scan1_k<<<NN/256, 256, 0, stream>>>(cnt, offs, bsum);
    scan2_k<<<1, 384, 0, stream>>>(bsum);
    scan3_k<<<NN/256, 256, 0, stream>>>(offs, bsum, cursor);
    scatter_k<<<ETOT/256, 256, 0, stream>>>(e0, e1i, cursor, perm);

    // ---- 1. GAT encoder ----
    gat_node_k<<<NN/256, 256, 0, stream>>>(x, mask, noise, W_enc, asrc_e, adst_e,
                                           xp, sval, dval, 1);
    gat_agg_k<<<NN/256, 256, 0, stream>>>(perm, offs, cnt, xp, sval, dval, b_enc, t, 0);

    // ---- 2. transformer layer ----
    dim3 g9(DD/64, MR/64);
    dim3 g32(FFD/64, MR/64);
    gemm_nt<<<g9, 256, 0, stream>>>(t, Wq, bq, q, MR, DD, DD, 0);
    gemm_nt<<<g9, 256, 0, stream>>>(t, Wk, bk, k, MR, DD, DD, 0);
    gemm_nt<<<g9, 256, 0, stream>>>(t, Wv, bv, v, MR, DD, DD, 0);
    attn_k<<<BB*HH*SS, 256, 0, stream>>>(q, k, v, t1);
    gemm_nt<<<g9, 256, 0, stream>>>(t1, Wo, bo, o, MR, DD, DD, 0);
    ln_k<<<MR, 256, 0, stream>>>(t, o, ln1g, ln1b, t1);
    gemm_nt<<<g32, 256, 0, stream>>>(t1, W1, b1, ff1, MR, FFD, DD, 1);
    gemm_nt<<<g9, 256, 0, stream>>>(ff1, W2, b2, o, MR, DD, FFD, 0);
    ln_k<<<MR, 256, 0, stream>>>(t1, o, ln2g, ln2b, t);

    // ---- 3. UNet1d (time-major activations, im2col + NT GEMM) ----
    wtrans_k<<<(576*576*3+255)/256, 256, 0, stream>>>(enc1_w, wT, 576, 576);
    im2col_k<<<(BB*512*576*3+255)/256, 256, 0, stream>>>(t, nullptr, col, 512, 512, 576, 1, 1, 0);
    gemm_nt<<<dim3(576/64, 2048/64), 256, 0, stream>>>(col, wT, enc1_b, e1, 2048, 576, 1728, 1);
    wtrans_k<<<(1152*576*3+255)/256, 256, 0, stream>>>(down_w, wT, 1152, 576);
    im2col_k<<<(BB*256*576*3+255)/256, 256, 0, stream>>>(e1, nullptr, col, 256, 512, 576, 2, 0, 0);
    gemm_nt<<<dim3(1152/64, 1024/64), 256, 0, stream>>>(col, wT, down_b, d1, 1024, 1152, 1728, 1);
    wtrans_k<<<(1152*1152*3+255)/256, 256, 0, stream>>>(bott_w, wT, 1152, 1152);
    im2col_k<<<(BB*256*1152*3+255)/256, 256, 0, stream>>>(d1, nullptr, col, 256, 256, 1152, 1, 1, 0);
    gemm_nt<<<dim3(1152/64, 1024/64), 256, 0, stream>>>(col, wT, bott_b, btb, 1024, 1152, 3456, 1);
    wtrans_k<<<(576*1152*3+255)/256, 256, 0, stream>>>(up_w, wT, 576, 1152);
    im2col_k<<<(BB*512*1152*3+255)/256, 256, 0, stream>>>(btb, nullptr, col, 512, 256, 1152, 1, 1, 1);
    gemm_nt<<<dim3(576/64, 2048/64), 256, 0, stream>>>(col, wT, up_b, up, 2048, 576, 3456, 1);
    wtrans_k<<<(576*1152*3+255)/256, 256, 0, stream>>>(dec_w, wT, 576, 1152);
    im2col_k<<<(BB*512*1152*3+255)/256, 256, 0, stream>>>(up, e1, col, 512, 512, 1152, 1, 1, 2);
    gemm_nt<<<dim3(576/64, 2048/64), 256, 0, stream>>>(col, wT, dec_b, dec, 2048, 576, 3456, 0);

    // ---- 4. GAT decoder + tanh ----
    gat_node_k<<<NN/256, 256, 0, stream>>>(dec, nullptr, nullptr, W_dec, asrc_d, adst_d,
                                           xp, sval, dval, 0);
    gat_agg_k<<<NN/256, 256, 0, stream>>>(perm, offs, cnt, xp, sval, dval, b_dec, out, 1);
}

// Round 3
// 789.976 us; speedup vs baseline: 5.9117x; 3.1646x over previous
//
#include <hip/hip_runtime.h>
#include <hip/hip_bf16.h>
#include <math.h>

// ---------------- problem constants ----------------
#define NN 98304            // nodes = B*S*G
#define CC 12               // node channels
#define EE 1572864          // edges (before self-loops)
#define ETOT (EE + NN)      // edges + self loops
#define BB 4
#define SS 512
#define DD 576              // d_model
#define HH 3
#define HDI 192
#define FFD 2048
#define MR (BB*SS)          // 2048 token rows
#define ND (NN*CC)
#define ATT_SCALE 0.07216878364870323f  // 1/sqrt(192)

typedef __hip_bfloat16 bf;
typedef __attribute__((ext_vector_type(8))) short s8v;
typedef __attribute__((ext_vector_type(4))) float f4v;

__device__ __forceinline__ void gl16(const void* g, void* l) {
    __builtin_amdgcn_global_load_lds(
        (const __attribute__((address_space(1))) unsigned int*)g,
        (__attribute__((address_space(3))) unsigned int*)l, 16, 0, 0);
}
__device__ __forceinline__ float ldf(const float* p) { return *p; }
__device__ __forceinline__ float ldf(const bf* p) { return __bfloat162float(*p); }

// ---------------- GAT: node transform ----------------
__global__ __launch_bounds__(256) void gat_node_k(
    const float* __restrict__ xin, const float* __restrict__ mask,
    const float* __restrict__ noise,
    const float* __restrict__ W, const float* __restrict__ a_s,
    const float* __restrict__ a_d,
    float* __restrict__ xp, float* __restrict__ sval, float* __restrict__ dval,
    int blend)
{
    int n = blockIdx.x * 256 + threadIdx.x;
    if (n >= NN) return;
    float h[CC];
#pragma unroll
    for (int c = 0; c < CC; ++c) {
        float v = xin[n*CC + c];
        if (blend) { float m = mask[n*CC+c]; v = v*m + noise[n*CC+c]*(1.0f-m); }
        h[c] = v;
    }
    float sv = 0.f, dv = 0.f;
#pragma unroll
    for (int oc = 0; oc < CC; ++oc) {
        float a = 0.f;
#pragma unroll
        for (int ic = 0; ic < CC; ++ic) a += h[ic]*W[oc*CC+ic];
        xp[n*CC+oc] = a;
        sv += a * a_s[oc]; dv += a * a_d[oc];
    }
    sval[n] = sv; dval[n] = dv;
}

// ---------------- counting sort of edges by dst ----------------
__global__ __launch_bounds__(256) void hist_k(
    const int* __restrict__ e1, int* __restrict__ cnt)
{
    for (long long i = blockIdx.x*256LL + threadIdx.x; i < ETOT; i += (long long)gridDim.x*256) {
        int d = (i < EE) ? e1[i] : (int)(i - EE);
        atomicAdd(&cnt[d], 1);
    }
}

__global__ __launch_bounds__(256) void scan1_k(
    const int* __restrict__ cnt, int* __restrict__ offs, int* __restrict__ bsum)
{
    __shared__ int sh[256];
    int b = blockIdx.x, t = threadIdx.x;
    int v = cnt[b*256 + t];
    sh[t] = v; __syncthreads();
    for (int off = 1; off < 256; off <<= 1) {
        int add = (t >= off) ? sh[t-off] : 0;
        __syncthreads();
        sh[t] += add;
        __syncthreads();
    }
    offs[b*256 + t] = sh[t] - v;
    if (t == 255) bsum[b] = sh[255];
}

__global__ __launch_bounds__(384) void scan2_k(int* __restrict__ bsum)
{
    __shared__ int sh[384];
    int t = threadIdx.x;
    sh[t] = bsum[t];
    __syncthreads();
    if (t == 0) { int run = 0; for (int i = 0; i < 384; ++i) { int v = sh[i]; sh[i] = run; run += v; } }
    __syncthreads();
    bsum[t] = sh[t];
}

__global__ __launch_bounds__(256) void scan3_k(
    int* __restrict__ offs, const int* __restrict__ bsum, int* __restrict__ cursor)
{
    int i = blockIdx.x*256 + threadIdx.x;
    int v = offs[i] + bsum[blockIdx.x];
    offs[i] = v; cursor[i] = v;
}

__global__ __launch_bounds__(256) void scatter_k(
    const int* __restrict__ e0, const int* __restrict__ e1,
    int* __restrict__ cursor, int* __restrict__ perm)
{
    for (long long i = blockIdx.x*256LL + threadIdx.x; i < ETOT; i += (long long)gridDim.x*256) {
        int s = (i < EE) ? e0[i] : (int)(i - EE);
        int d = (i < EE) ? e1[i] : (int)(i - EE);
        int pos = atomicAdd(&cursor[d], 1);
        perm[pos] = s;
    }
}

// ---------------- GAT: segmented gather-aggregate ----------------
__global__ __launch_bounds__(256) void gat_agg_k(
    const int* __restrict__ perm, const int* __restrict__ offs,
    const int* __restrict__ cnt,
    const float* __restrict__ xp, const float* __restrict__ sval,
    const float* __restrict__ dval, const float* __restrict__ bias,
    float* __restrict__ out, bf* __restrict__ outb, int dotanh)
{
    int n = blockIdx.x*256 + threadIdx.x;
    if (n >= NN) return;
    int beg = offs[n], m = cnt[n];
    float dv = dval[n];
    float acc[CC] = {};
    float den = 0.f;
    for (int i = 0; i < m; ++i) {
        int s = perm[beg + i];
        float e = sval[s] + dv;
        e = e > 0.f ? e : 0.2f*e;
        float w = __expf(e);
        den += w;
        const float4* xr = (const float4*)(xp + (size_t)s*CC);
        float4 p0 = xr[0], p1 = xr[1], p2 = xr[2];
        acc[0] += w*p0.x; acc[1] += w*p0.y; acc[2]  += w*p0.z; acc[3]  += w*p0.w;
        acc[4] += w*p1.x; acc[5] += w*p1.y; acc[6]  += w*p1.z; acc[7]  += w*p1.w;
        acc[8] += w*p2.x; acc[9] += w*p2.y; acc[10] += w*p2.z; acc[11] += w*p2.w;
    }
    float inv = 1.f / den;
#pragma unroll
    for (int c = 0; c < CC; ++c) {
        float r = acc[c]*inv + bias[c];
        if (dotanh) r = tanhf(r);
        if (out)  out[n*CC + c] = r;
        if (outb) outb[n*CC + c] = __float2bfloat16(r);
    }
}

// ---------------- bf16 MFMA NT GEMM ----------------
// C[M,N] = A[M,K] @ B[N,K]^T (+bias)(*scale)(relu); batched via z=(z1*bdiv+z2)
// BM=128, BN=64, BK=32, 256 threads (4 waves, 2x2), 16x16x32 bf16 MFMA
__global__ __launch_bounds__(256) void gemm_bt(
    const bf* __restrict__ A, const bf* __restrict__ B,
    const float* __restrict__ bias, float* __restrict__ Cf, bf* __restrict__ Cb,
    int K, int lda, int ldb, int ldc,
    long long sA1, long long sA2, long long sB1, long long sB2,
    long long sC1, long long sC2, int bdiv,
    float scale, int relu)
{
    __shared__ bf As[128*32];   // 8 KB
    __shared__ bf Bs[64*32];    // 4 KB
    const int tid = threadIdx.x, lane = tid & 63, wave = tid >> 6;
    const int z = blockIdx.z, z1 = z / bdiv, z2 = z % bdiv;
    const bf* Ab = A + z1*sA1 + z2*sA2;
    const bf* Bb = B + z1*sB1 + z2*sB2;
    const int bm = blockIdx.y * 128, bn = blockIdx.x * 64;
    const int l4 = lane >> 2;            // 0..15 (row within 16-row chunk)
    const int lc = (lane & 3) * 8;       // element col offset (16B granules)
    const int arow0 = wave*32 + l4;      // each wave stages 32 A-rows
    const int arow1 = arow0 + 16;
    const int brow  = wave*16 + l4;      // each wave stages 16 B-rows
    const int wm = wave >> 1, wn = wave & 1;
    const int fr = lane & 15, fk = (lane >> 4) * 8;
    f4v acc[4][2] = {};

    for (int k0 = 0; k0 < K; k0 += 32) {
        gl16(Ab + (size_t)(bm + arow0)*lda + k0 + lc, As + wave*1024);
        gl16(Ab + (size_t)(bm + arow1)*lda + k0 + lc, As + wave*1024 + 512);
        gl16(Bb + (size_t)(bn + brow )*ldb + k0 + lc, Bs + wave*512);
        __syncthreads();
        s8v af[4], bfv[2];
#pragma unroll
        for (int mi = 0; mi < 4; ++mi)
            af[mi] = *(const s8v*)&As[(wm*64 + mi*16 + fr)*32 + fk];
#pragma unroll
        for (int nj = 0; nj < 2; ++nj)
            bfv[nj] = *(const s8v*)&Bs[(wn*32 + nj*16 + fr)*32 + fk];
#pragma unroll
        for (int mi = 0; mi < 4; ++mi)
#pragma unroll
            for (int nj = 0; nj < 2; ++nj)
                acc[mi][nj] = __builtin_amdgcn_mfma_f32_16x16x32_bf16(
                    af[mi], bfv[nj], acc[mi][nj], 0, 0, 0);
        __syncthreads();
    }

    float* Cfb = Cf ? Cf + z1*sC1 + z2*sC2 : nullptr;
    bf*    Cbb = Cb ? Cb + z1*sC1 + z2*sC2 : nullptr;
#pragma unroll
    for (int mi = 0; mi < 4; ++mi) {
#pragma unroll
        for (int nj = 0; nj < 2; ++nj) {
            int col = bn + wn*32 + nj*16 + fr;
            float bv = bias ? bias[col] : 0.f;
#pragma unroll
            for (int r = 0; r < 4; ++r) {
                int row = bm + wm*64 + mi*16 + (lane>>4)*4 + r;
                float vv = (acc[mi][nj][r] + bv) * scale;
                if (relu) vv = fmaxf(vv, 0.f);
                if (Cfb) Cfb[(size_t)row*ldc + col] = vv;
                if (Cbb) Cbb[(size_t)row*ldc + col] = __float2bfloat16(vv);
            }
        }
    }
}

// ---------------- softmax rows of 512, f32 -> bf16 ----------------
__global__ __launch_bounds__(256) void softmax_k(
    const float* __restrict__ S, bf* __restrict__ P)
{
    int row = blockIdx.x; size_t base = (size_t)row * SS;
    int tid = threadIdx.x;
    __shared__ float red[256];
    float v0 = S[base+tid], v1 = S[base+tid+256];
    red[tid] = fmaxf(v0, v1); __syncthreads();
    for (int off = 128; off > 0; off >>= 1) {
        if (tid < off) red[tid] = fmaxf(red[tid], red[tid+off]);
        __syncthreads();
    }
    float mx = red[0]; __syncthreads();
    float e0 = __expf(v0-mx), e1 = __expf(v1-mx);
    red[tid] = e0+e1; __syncthreads();
    for (int off = 128; off > 0; off >>= 1) {
        if (tid < off) red[tid] += red[tid+off];
        __syncthreads();
    }
    float inv = 1.f / red[0];
    P[base+tid]     = __float2bfloat16(e0*inv);
    P[base+tid+256] = __float2bfloat16(e1*inv);
}

// ---------------- v[b,s,h,d] bf16 -> vt[(b,h)][d][s] bf16 ----------------
__global__ __launch_bounds__(256) void vtrans_k(
    const bf* __restrict__ vb, bf* __restrict__ vt)
{
    int idx = blockIdx.x*256 + threadIdx.x;   // 12*192*512
    int z = idx / (HDI*SS); int r = idx % (HDI*SS);
    int d = r / SS; int s = r % SS;
    int b = z / HH, h = z % HH;
    vt[idx] = vb[((size_t)(b*SS + s))*DD + h*HDI + d];
}

// ---------------- f32 -> bf16 cast ----------------
__global__ __launch_bounds__(256) void castw_k(
    const float* __restrict__ w, bf* __restrict__ o, int n)
{
    for (int i = blockIdx.x*256 + threadIdx.x; i < n; i += gridDim.x*256)
        o[i] = __float2bfloat16(w[i]);
}

// ---------------- layernorm over D=576 (writes f32 + optional bf16) --------
__global__ __launch_bounds__(256) void ln_k(
    const float* __restrict__ a, const float* __restrict__ r,
    const float* __restrict__ g, const float* __restrict__ be,
    float* __restrict__ out, bf* __restrict__ ob)
{
    int row = blockIdx.x; int tid = threadIdx.x;
    __shared__ float red[256], red2[256];
    size_t base = (size_t)row * DD;
    float x0 = a[base+tid]      + r[base+tid];
    float x1 = a[base+tid+256]  + r[base+tid+256];
    float x2 = (tid < 64) ? (a[base+tid+512] + r[base+tid+512]) : 0.f;
    float s  = x0+x1+x2;
    float s2 = x0*x0 + x1*x1 + x2*x2;
    red[tid] = s; red2[tid] = s2; __syncthreads();
    for (int off = 128; off > 0; off >>= 1) {
        if (tid < off) { red[tid] += red[tid+off]; red2[tid] += red2[tid+off]; }
        __syncthreads();
    }
    float mean = red[0] / (float)DD;
    float var  = red2[0] / (float)DD - mean*mean;
    float inv = rsqrtf(var + 1e-5f);
    float y0 = (x0-mean)*inv*g[tid]     + be[tid];
    float y1 = (x1-mean)*inv*g[tid+256] + be[tid+256];
    out[base+tid]     = y0;
    out[base+tid+256] = y1;
    if (ob) { ob[base+tid] = __float2bfloat16(y0); ob[base+tid+256] = __float2bfloat16(y1); }
    if (tid < 64) {
        float y2 = (x2-mean)*inv*g[tid+512] + be[tid+512];
        out[base+tid+512] = y2;
        if (ob) ob[base+tid+512] = __float2bfloat16(y2);
    }
}

// ---------------- conv helpers ----------------
// w[co][ci][k] f32 -> wT[co][k][ci] bf16
__global__ __launch_bounds__(256) void wtrans_k(
    const float* __restrict__ w, bf* __restrict__ wT, int Cout, int Cin)
{
    int total = Cout * Cin * 3;
    for (int i = blockIdx.x*256 + threadIdx.x; i < total; i += gridDim.x*256) {
        int co = i / (Cin*3); int rem = i % (Cin*3);
        int ci = rem / 3; int kk = rem % 3;
        wT[(size_t)co*Cin*3 + kk*Cin + ci] = __float2bfloat16(w[i]);
    }
}

// im2col from time-major [B, Lin, Cin] -> col[B*Lout][3*Cin] bf16 (k-major)
template<typename T>
__global__ __launch_bounds__(256) void im2col_k(
    const T* __restrict__ s0, const T* __restrict__ s1,
    bf* __restrict__ col, int Lout, int Lin, int Cin,
    int stride, int pad, int mode)
{
    long long total = (long long)BB * Lout * Cin * 3;
    for (long long i = blockIdx.x*256LL + threadIdx.x; i < total; i += (long long)gridDim.x*256) {
        int j = (int)(i % (Cin*3));
        long long m = i / (Cin*3);
        int l = (int)(m % Lout); int b = (int)(m / Lout);
        int kk = j / Cin; int ci = j % Cin;
        int sl = l*stride + kk - pad;
        int Lsrc = (mode == 1) ? Lin*2 : Lin;
        float v = 0.f;
        if (sl >= 0 && sl < Lsrc) {
            if (mode == 1)       v = ldf(&s0[((size_t)b*Lin + (sl >> 1))*Cin + ci]);
            else if (mode == 2)  v = (ci < Cin/2)
                                   ? ldf(&s0[((size_t)b*Lin + sl)*(Cin/2) + ci])
                                   : ldf(&s1[((size_t)b*Lin + sl)*(Cin/2) + (ci - Cin/2)]);
            else                 v = ldf(&s0[((size_t)b*Lin + sl)*Cin + ci]);
        }
        col[i] = __float2bfloat16(v);
    }
}

// ---------------- launch ----------------
extern "C" void kernel_launch(void* const* d_in, const int* in_sizes, int n_in,
                              void* d_out, int out_size, void* d_ws, size_t ws_size,
                              hipStream_t stream)
{
    const int*   edge   = (const int*)  d_in[0];
    const float* x      = (const float*)d_in[1];
    const float* mask   = (const float*)d_in[2];
    const float* noise  = (const float*)d_in[3];
    const float* W_enc  = (const float*)d_in[4];
    const float* asrc_e = (const float*)d_in[5];
    const float* adst_e = (const float*)d_in[6];
    const float* b_enc  = (const float*)d_in[7];
    const float* Wq = (const float*)d_in[8];  const float* bq = (const float*)d_in[9];
    const float* Wk = (const float*)d_in[10]; const float* bk = (const float*)d_in[11];
    const float* Wv = (const float*)d_in[12]; const float* bv = (const float*)d_in[13];
    const float* Wo = (const float*)d_in[14]; const float* bo = (const float*)d_in[15];
    const float* ln1g = (const float*)d_in[16]; const float* ln1b = (const float*)d_in[17];
    const float* W1 = (const float*)d_in[18]; const float* b1 = (const float*)d_in[19];
    const float* W2 = (const float*)d_in[20]; const float* b2 = (const float*)d_in[21];
    const float* ln2g = (const float*)d_in[22]; const float* ln2b = (const float*)d_in[23];
    const float* enc1_w = (const float*)d_in[24]; const float* enc1_b = (const float*)d_in[25];
    const float* down_w = (const float*)d_in[26]; const float* down_b = (const float*)d_in[27];
    const float* bott_w = (const float*)d_in[28]; const float* bott_b = (const float*)d_in[29];
    const float* up_w   = (const float*)d_in[30]; const float* up_b   = (const float*)d_in[31];
    const float* dec_w  = (const float*)d_in[32]; const float* dec_b  = (const float*)d_in[33];
    const float* W_dec  = (const float*)d_in[34];
    const float* asrc_d = (const float*)d_in[35];
    const float* adst_d = (const float*)d_in[36];
    const float* b_dec  = (const float*)d_in[37];
    float* out = (float*)d_out;

    float* ws = (float*)d_ws;
    // float-unit offsets; total 24,104,960 floats = 96.4 MB
    float* xp   = ws;                        // 1179648
    float* sval = ws + 1179648;              // 98304
    float* dval = ws + 1277952;              // 98304
    int*   cnt  = (int*)(ws + 1376256);      // 98304
    int*   offs = (int*)(ws + 1474560);      // 98304
    int*   perm = (int*)(ws + 1572864);      // 1671168
    float* t    = ws + 3244032;              // 1179648
    bf*    tb   = (bf*)(ws + 4423680);       // 589824 f
    bf*    qb   = (bf*)(ws + 5013504);       // 589824 f
    bf*    kb   = (bf*)(ws + 5603328);       // 589824 f
    bf*    vb   = (bf*)(ws + 6193152);       // 589824 f
    float* big  = ws + 6782976;              // 4718592 f shared scratch
    float* scores = big;                     // 3145728 f (attention phase)
    bf*    Pb   = (bf*)(big + 3145728);      // 1572864 f (attention phase)
    bf*    colb = (bf*)big;                  // conv phase (up to 3538944 f)
    float* o    = ws + 11501568;             // 1179648
    float* t1   = ws + 12681216;             // 1179648
    bf*    t1b  = (bf*)(ws + 13860864);      // 589824 f
    bf*    ff1b = (bf*)(ws + 14450688);      // 2097152 f
    float* t2   = ws + 16547840;             // 1179648
    bf*    e1b  = (bf*)(ws + 17727488);      // 589824 f
    bf*    d1b  = (bf*)(ws + 18317312);      // 589824 f
    bf*    btbb = (bf*)(ws + 18907136);      // 589824 f
    bf*    upb  = (bf*)(ws + 19496960);      // 589824 f
    float* dec  = ws + 20086784;             // 1179648
    bf*    wTb  = (bf*)(ws + 21266432);      // 995328 f
    bf*    Wqb  = (bf*)(ws + 22261760);      // 165888 f
    bf*    Wkb  = (bf*)(ws + 22427648);
    bf*    Wvb  = (bf*)(ws + 22593536);
    bf*    Wob  = (bf*)(ws + 22759424);
    bf*    W1b  = (bf*)(ws + 22925312);      // 589824 f
    bf*    W2b  = (bf*)(ws + 23515136);      // 589824 f, end 24104960
    bf*    vt    = kb;                       // alias: kb dead after scores GEMM
    bf*    attnO = qb;                       // alias: qb dead after scores GEMM
    int*   cursor = (int*)(ws + 11501568);   // alias o (dead during sort)
    int*   bsum   = (int*)(ws + 12681216);   // alias t1 (dead during sort)

    const int* e0 = edge;
    const int* e1i = edge + EE;

    // ---- 0. dst-sorted edge permutation (shared by both GATs) ----
    hipMemsetAsync(cnt, 0, NN*sizeof(int), stream);
    hist_k<<<ETOT/256, 256, 0, stream>>>(e1i, cnt);
    scan1_k<<<NN/256, 256, 0, stream>>>(cnt, offs, bsum);
    scan2_k<<<1, 384, 0, stream>>>(bsum);
    scan3_k<<<NN/256, 256, 0, stream>>>(offs, bsum, cursor);
    scatter_k<<<ETOT/256, 256, 0, stream>>>(e0, e1i, cursor, perm);

    // ---- weight casts ----
    castw_k<<<324, 256, 0, stream>>>(Wq, Wqb, DD*DD);
    castw_k<<<324, 256, 0, stream>>>(Wk, Wkb, DD*DD);
    castw_k<<<324, 256, 0, stream>>>(Wv, Wvb, DD*DD);
    castw_k<<<324, 256, 0, stream>>>(Wo, Wob, DD*DD);
    castw_k<<<1152, 256, 0, stream>>>(W1, W1b, FFD*DD);
    castw_k<<<1152, 256, 0, stream>>>(W2, W2b, FFD*DD);

    // ---- 1. GAT encoder ----
    gat_node_k<<<NN/256, 256, 0, stream>>>(x, mask, noise, W_enc, asrc_e, adst_e,
                                           xp, sval, dval, 1);
    gat_agg_k<<<NN/256, 256, 0, stream>>>(perm, offs, cnt, xp, sval, dval, b_enc,
                                          t, tb, 0);

    // ---- 2. transformer layer ----
    // QKV (scale folded into q)
    gemm_bt<<<dim3(9,16,1), 256, 0, stream>>>(tb, Wqb, bq, nullptr, qb,
        DD, DD, DD, DD, 0,0,0,0,0,0, 1, ATT_SCALE, 0);
    gemm_bt<<<dim3(9,16,1), 256, 0, stream>>>(tb, Wkb, bk, nullptr, kb,
        DD, DD, DD, DD, 0,0,0,0,0,0, 1, 1.f, 0);
    gemm_bt<<<dim3(9,16,1), 256, 0, stream>>>(tb, Wvb, bv, nullptr, vb,
        DD, DD, DD, DD, 0,0,0,0,0,0, 1, 1.f, 0);
    // scores[z][512][512] = q @ k^T  (z = b*3+h)
    gemm_bt<<<dim3(8,4,12), 256, 0, stream>>>(qb, kb, nullptr, scores, nullptr,
        HDI, DD, DD, SS,
        (long long)SS*DD, HDI, (long long)SS*DD, HDI,
        3LL*SS*SS, (long long)SS*SS, HH, 1.f, 0);
    softmax_k<<<12*SS, 256, 0, stream>>>(scores, Pb);
    vtrans_k<<<4608, 256, 0, stream>>>(vb, vt);
    // O[z] = P @ vt^T -> attnO[b*512+q][h*192+d]
    gemm_bt<<<dim3(3,4,12), 256, 0, stream>>>(Pb, vt, nullptr, nullptr, attnO,
        SS, SS, SS, DD,
        3LL*SS*SS, (long long)SS*SS, 3LL*HDI*SS, (long long)HDI*SS,
        (long long)SS*DD, HDI, HH, 1.f, 0);
    gemm_bt<<<dim3(9,16,1), 256, 0, stream>>>(attnO, Wob, bo, o, nullptr,
        DD, DD, DD, DD, 0,0,0,0,0,0, 1, 1.f, 0);
    ln_k<<<MR, 256, 0, stream>>>(t, o, ln1g, ln1b, t1, t1b);
    gemm_bt<<<dim3(32,16,1), 256, 0, stream>>>(t1b, W1b, b1, nullptr, ff1b,
        DD, DD, DD, FFD, 0,0,0,0,0,0, 1, 1.f, 1);
    gemm_bt<<<dim3(9,16,1), 256, 0, stream>>>(ff1b, W2b, b2, o, nullptr,
        FFD, FFD, FFD, DD, 0,0,0,0,0,0, 1, 1.f, 0);
    ln_k<<<MR, 256, 0, stream>>>(t1, o, ln2g, ln2b, t2, nullptr);

    // ---- 3. UNet1d ----
    // enc1: 576 -> 576, L=512
    wtrans_k<<<2048, 256, 0, stream>>>(enc1_w, wTb, 576, 576);
    im2col_k<float><<<4096, 256, 0, stream>>>(t2, nullptr, colb, 512, 512, 576, 1, 1, 0);
    gemm_bt<<<dim3(9,16,1), 256, 0, stream>>>(colb, wTb, enc1_b, nullptr, e1b,
        1728, 1728, 1728, 576, 0,0,0,0,0,0, 1, 1.f, 1);
    // down: 576 -> 1152, L 512->256 stride 2
    wtrans_k<<<4096, 256, 0, stream>>>(down_w, wTb, 1152, 576);
    im2col_k<bf><<<4096, 256, 0, stream>>>(e1b, nullptr, colb, 256, 512, 576, 2, 0, 0);
    gemm_bt<<<dim3(18,8,1), 256, 0, stream>>>(colb, wTb, down_b, nullptr, d1b,
        1728, 1728, 1728, 1152, 0,0,0,0,0,0, 1, 1.f, 1);
    // bott: 1152 -> 1152, L=256
    wtrans_k<<<8192, 256, 0, stream>>>(bott_w, wTb, 1152, 1152);
    im2col_k<bf><<<4096, 256, 0, stream>>>(d1b, nullptr, colb, 256, 256, 1152, 1, 1, 0);
    gemm_bt<<<dim3(18,8,1), 256, 0, stream>>>(colb, wTb, bott_b, nullptr, btbb,
        3456, 3456, 3456, 1152, 0,0,0,0,0,0, 1, 1.f, 1);
    // up: repeat x2 then 1152 -> 576, L=512
    wtrans_k<<<4096, 256, 0, stream>>>(up_w, wTb, 576, 1152);
    im2col_k<bf><<<4096, 256, 0, stream>>>(btbb, nullptr, colb, 512, 256, 1152, 1, 1, 1);
    gemm_bt<<<dim3(9,16,1), 256, 0, stream>>>(colb, wTb, up_b, nullptr, upb,
        3456, 3456, 3456, 576, 0,0,0,0,0,0, 1, 1.f, 1);
    // dec: concat(up, e1) 1152 -> 576, no relu, f32 out
    wtrans_k<<<4096, 256, 0, stream>>>(dec_w, wTb, 576, 1152);
    im2col_k<bf><<<4096, 256, 0, stream>>>(upb, e1b, colb, 512, 512, 1152, 1, 1, 2);
    gemm_bt<<<dim3(9,16,1), 256, 0, stream>>>(colb, wTb, dec_b, dec, nullptr,
        3456, 3456, 3456, 576, 0,0,0,0,0,0, 1, 1.f, 0);

    // ---- 4. GAT decoder + tanh ----
    gat_node_k<<<NN/256, 256, 0, stream>>>(dec, nullptr, nullptr, W_dec, asrc_d, adst_d,
                                           xp, sval, dval, 0);
    gat_agg_k<<<NN/256, 256, 0, stream>>>(perm, offs, cnt, xp, sval, dval, b_dec,
                                          out, nullptr, 1);
}